// Round 2
// baseline (298.262 us; speedup 1.0000x reference)
//
#include <hip/hip_runtime.h>
#include <math.h>

#define COS_EPS 1e-8f

typedef float vfloat4 __attribute__((ext_vector_type(4)));

// One wave (64 lanes) per sample, grid-stride unrolled x2 for memory-level
// parallelism. Per sample: lane loads float4 chunks of the embedding row
// (non-temporal: read-once, keep L2/LLC for the prototype table) and the
// gathered prototype row; computes dot, |e|^2, |p|^2; 64-lane butterfly
// reduce; lane 0 accumulates cos. Block partial -> d_ws; ticket-atomic
// "last block" reduces all partials and writes 1 - mean directly to d_out
// (no separate finalize launch).
__global__ __launch_bounds__(256) void assignment_loss_kernel(
    const float* __restrict__ emb,      // [B, D]
    const int*   __restrict__ labels,   // [B]
    const float* __restrict__ protos,   // [C, D]
    float*        __restrict__ partials, // [gridDim.x]
    unsigned int* __restrict__ ticket,   // [1], pre-zeroed
    float*        __restrict__ out,      // [1]
    int B, int D, float invB)
{
    const int lane          = threadIdx.x & 63;
    const int wave_in_block = threadIdx.x >> 6;
    const int waves_per_blk = blockDim.x >> 6;
    const int global_wave   = blockIdx.x * waves_per_blk + wave_in_block;
    const int n_waves       = gridDim.x * waves_per_blk;
    const int nchunks       = D >> 8;   // 256 floats per chunk (64 lanes * float4)

    float local = 0.0f;

    for (int s0 = global_wave; s0 < B; s0 += 2 * n_waves) {
        const int s1    = s0 + n_waves;
        const bool has1 = (s1 < B);

        const int l0 = labels[s0];
        const int l1 = has1 ? labels[s1] : 0;

        const vfloat4* __restrict__ e0 = (const vfloat4*)(emb    + (size_t)s0 * (size_t)D);
        const vfloat4* __restrict__ p0 = (const vfloat4*)(protos + (size_t)l0 * (size_t)D);
        const vfloat4* __restrict__ e1 = (const vfloat4*)(emb    + (size_t)(has1 ? s1 : s0) * (size_t)D);
        const vfloat4* __restrict__ p1 = (const vfloat4*)(protos + (size_t)l1 * (size_t)D);

        float dot0 = 0.f, esq0 = 0.f, psq0 = 0.f;
        float dot1 = 0.f, esq1 = 0.f, psq1 = 0.f;

        #pragma unroll
        for (int c = 0; c < 2; ++c) {           // D=512 -> exactly 2 chunks
            if (c < nchunks) {
                vfloat4 ev0 = __builtin_nontemporal_load(&e0[c * 64 + lane]);
                vfloat4 pv0 = p0[c * 64 + lane];
                vfloat4 ev1 = __builtin_nontemporal_load(&e1[c * 64 + lane]);
                vfloat4 pv1 = p1[c * 64 + lane];

                dot0 = fmaf(ev0.x, pv0.x, fmaf(ev0.y, pv0.y, fmaf(ev0.z, pv0.z, fmaf(ev0.w, pv0.w, dot0))));
                esq0 = fmaf(ev0.x, ev0.x, fmaf(ev0.y, ev0.y, fmaf(ev0.z, ev0.z, fmaf(ev0.w, ev0.w, esq0))));
                psq0 = fmaf(pv0.x, pv0.x, fmaf(pv0.y, pv0.y, fmaf(pv0.z, pv0.z, fmaf(pv0.w, pv0.w, psq0))));
                dot1 = fmaf(ev1.x, pv1.x, fmaf(ev1.y, pv1.y, fmaf(ev1.z, pv1.z, fmaf(ev1.w, pv1.w, dot1))));
                esq1 = fmaf(ev1.x, ev1.x, fmaf(ev1.y, ev1.y, fmaf(ev1.z, ev1.z, fmaf(ev1.w, ev1.w, esq1))));
                psq1 = fmaf(pv1.x, pv1.x, fmaf(pv1.y, pv1.y, fmaf(pv1.z, pv1.z, fmaf(pv1.w, pv1.w, psq1))));
            }
        }
        // generic tail for D > 512 (not hit for this problem shape)
        for (int c = 2; c < nchunks; ++c) {
            vfloat4 ev0 = __builtin_nontemporal_load(&e0[c * 64 + lane]);
            vfloat4 pv0 = p0[c * 64 + lane];
            vfloat4 ev1 = __builtin_nontemporal_load(&e1[c * 64 + lane]);
            vfloat4 pv1 = p1[c * 64 + lane];
            dot0 = fmaf(ev0.x, pv0.x, fmaf(ev0.y, pv0.y, fmaf(ev0.z, pv0.z, fmaf(ev0.w, pv0.w, dot0))));
            esq0 = fmaf(ev0.x, ev0.x, fmaf(ev0.y, ev0.y, fmaf(ev0.z, ev0.z, fmaf(ev0.w, ev0.w, esq0))));
            psq0 = fmaf(pv0.x, pv0.x, fmaf(pv0.y, pv0.y, fmaf(pv0.z, pv0.z, fmaf(pv0.w, pv0.w, psq0))));
            dot1 = fmaf(ev1.x, pv1.x, fmaf(ev1.y, pv1.y, fmaf(ev1.z, pv1.z, fmaf(ev1.w, pv1.w, dot1))));
            esq1 = fmaf(ev1.x, ev1.x, fmaf(ev1.y, ev1.y, fmaf(ev1.z, ev1.z, fmaf(ev1.w, ev1.w, esq1))));
            psq1 = fmaf(pv1.x, pv1.x, fmaf(pv1.y, pv1.y, fmaf(pv1.z, pv1.z, fmaf(pv1.w, pv1.w, psq1))));
        }

        // 64-lane butterfly reduction (wave = 64 on CDNA)
        #pragma unroll
        for (int off = 32; off > 0; off >>= 1) {
            dot0 += __shfl_xor(dot0, off, 64);
            esq0 += __shfl_xor(esq0, off, 64);
            psq0 += __shfl_xor(psq0, off, 64);
            dot1 += __shfl_xor(dot1, off, 64);
            esq1 += __shfl_xor(esq1, off, 64);
            psq1 += __shfl_xor(psq1, off, 64);
        }

        if (lane == 0) {
            float en0 = fmaxf(sqrtf(esq0), COS_EPS);  // torch F.cosine_similarity eps semantics
            float pn0 = fmaxf(sqrtf(psq0), COS_EPS);
            local += dot0 / (en0 * pn0);
            if (has1) {
                float en1 = fmaxf(sqrtf(esq1), COS_EPS);
                float pn1 = fmaxf(sqrtf(psq1), COS_EPS);
                local += dot1 / (en1 * pn1);
            }
        }
    }

    // block reduction: one partial per wave -> LDS -> per-block partial
    __shared__ float smem[8];
    __shared__ bool  am_last;
    if (lane == 0) smem[wave_in_block] = local;
    __syncthreads();
    if (threadIdx.x == 0) {
        float bs = 0.0f;
        for (int w = 0; w < waves_per_blk; ++w) bs += smem[w];
        partials[blockIdx.x] = bs;
        __threadfence();                          // make partial visible device-wide
        unsigned t = atomicAdd(ticket, 1u);       // device-scope by default
        am_last = (t == (unsigned)gridDim.x - 1u);
    }
    __syncthreads();

    if (am_last) {
        __threadfence();                          // acquire: see all partials
        float s = 0.0f;
        for (int i = threadIdx.x; i < gridDim.x; i += blockDim.x) s += partials[i];
        #pragma unroll
        for (int off = 32; off > 0; off >>= 1) s += __shfl_xor(s, off, 64);
        if (lane == 0) smem[wave_in_block] = s;
        __syncthreads();
        if (threadIdx.x == 0) {
            float total = 0.0f;
            for (int w = 0; w < waves_per_blk; ++w) total += smem[w];
            out[0] = 1.0f - total * invB;
        }
    }
}

extern "C" void kernel_launch(void* const* d_in, const int* in_sizes, int n_in,
                              void* d_out, int out_size, void* d_ws, size_t ws_size,
                              hipStream_t stream) {
    const float* emb    = (const float*)d_in[0];   // [B, D] float32
    const int*   labels = (const int*)  d_in[1];   // [B] int
    const float* protos = (const float*)d_in[2];   // [C, D] float32
    float*       out    = (float*)d_out;           // scalar float32

    unsigned int* ticket   = (unsigned int*)d_ws;                 // 4 B, must be zero
    float*        partials = (float*)((char*)d_ws + 256);         // [grid]

    const int B = in_sizes[1];
    const int D = in_sizes[0] / B;                 // 512

    hipMemsetAsync(ticket, 0, sizeof(unsigned int), stream);      // d_ws is poisoned 0xAA each call

    const int block = 256;                         // 4 waves/block
    const int grid  = 2048;                        // 8 blocks/CU target, 8192 waves
    assignment_loss_kernel<<<grid, block, 0, stream>>>(
        emb, labels, protos, partials, ticket, out, B, D, 1.0f / (float)B);
}